// Round 3
// baseline (1951.307 us; speedup 1.0000x reference)
//
#include <hip/hip_runtime.h>
#include <hip/hip_bf16.h>

// Expert-choice MoE, MI355X. B=4,S=4096,D=1024,E=8,I=4096, k=1024 per (b,e).
// R6: both GEMMs rebuilt as ring-of-4 LDS counted-vmcnt pipelines (T3+T4+T5):
//  - 512 threads / 8 waves (2Mx4N), BK=32, 4 LDS slots, stage tile kt+3 while
//    computing tile kt; one raw s_barrier per K-tile; s_waitcnt vmcnt(8) in
//    steady state (never drain to 0 in the main loop).
//  - global_load_lds staging with k-major chunk permutation of the GLOBAL
//    source (LDS dest stays linear) -> ds_read_b128 is bank-conflict-free.
//  - gemm1 fused: BM=256, BN=128 per matrix; G and U share the staged A-tile.
//  - gemm2: 256x256. setprio(1) around MFMA clusters.

#define B_ 4
#define S_ 4096
#define D_ 1024
#define E_ 8
#define I_ 4096
#define KCAP 1024
#define NGROUPS 32

typedef __bf16 bf16x8 __attribute__((ext_vector_type(8)));
typedef float floatx4 __attribute__((ext_vector_type(4)));

// direct global->LDS async copy, 16B per lane; lptr must be wave-uniform
#define GLD16(gptr, lptr)                                          \
  __builtin_amdgcn_global_load_lds(                                \
      (const __attribute__((address_space(1))) void*)(gptr),       \
      (__attribute__((address_space(3))) void*)(lptr), 16, 0, 0)

#define WAITV(N) asm volatile("s_waitcnt vmcnt(" #N ")" ::: "memory")
#define RAW_BAR() __builtin_amdgcn_s_barrier()
#define CFENCE() asm volatile("" ::: "memory")

__device__ __forceinline__ float bf2f(unsigned short h) {
  union { unsigned int u; float f; } v; v.u = ((unsigned int)h) << 16; return v.f;
}
__device__ __forceinline__ unsigned short f2bf(float f) {
  union { float f; unsigned int u; } v; v.f = f;
  unsigned int r = (v.u + 0x7fffu + ((v.u >> 16) & 1u)) >> 16;
  return (unsigned short)r;
}

// ---------------- 0. dtype probe: is d_in[0] fp32 (1) or bf16 (0)? ----------------
__global__ __launch_bounds__(256) void probe_dtype_k(const unsigned short* __restrict__ xr,
                                                     int* __restrict__ flag) {
  __shared__ unsigned int cnt;
  if (threadIdx.x == 0) cnt = 0;
  __syncthreads();
  unsigned int local = 0;
  for (int j = 0; j < 16; ++j) {
    int k = threadIdx.x * 16 + j;          // sample index
    unsigned short u = xr[2 * k];          // even bf16 position
    unsigned int expf = (u >> 7) & 0xFF;
    if (expf >= 0x90 && expf != 0xFF) local++;  // |v| >= 2^17 (wild for N(0,1))
    if (expf == 0xFF) local++;                   // inf/nan pattern
  }
  atomicAdd(&cnt, local);
  __syncthreads();
  if (threadIdx.x == 0) *flag = (cnt > 256u) ? 1 : 0;
}

// ---------------- 0b. convert input tensor -> canonical bf16 ----------------
__global__ __launch_bounds__(256) void conv_in_k(const void* __restrict__ src,
                                                 unsigned short* __restrict__ dst,
                                                 const int* __restrict__ flag) {
  const int isf32 = *flag;
  size_t i = ((size_t)blockIdx.x * 256 + threadIdx.x) * 8;
  if (isf32) {
    const float* s = (const float*)src;
    float4 a = *(const float4*)(s + i);
    float4 b = *(const float4*)(s + i + 4);
    ushort4 o0, o1;
    o0.x = f2bf(a.x); o0.y = f2bf(a.y); o0.z = f2bf(a.z); o0.w = f2bf(a.w);
    o1.x = f2bf(b.x); o1.y = f2bf(b.y); o1.z = f2bf(b.z); o1.w = f2bf(b.w);
    *(ushort4*)(dst + i) = o0;
    *(ushort4*)(dst + i + 4) = o1;
  } else {
    const uint4* s = (const uint4*)src;
    *(uint4*)(dst + i) = s[i / 8];
  }
}

// ---------------- 1. gate logits + softmax (fp64, native-precision reads) ----------------
__global__ __launch_bounds__(256) void gate_softmax_k(
    const void* __restrict__ xr, const void* __restrict__ gwr,
    const int* __restrict__ flag, double* __restrict__ aff) {
  const int isf32 = *flag;
  const int wave = threadIdx.x >> 6, lane = threadIdx.x & 63;
  const int token = blockIdx.x * 4 + wave;
  double acc[E_];
#pragma unroll
  for (int e2 = 0; e2 < E_; ++e2) acc[e2] = 0.0;
  for (int j = 0; j < 16; ++j) {
    int k = lane + 64 * j;
    double xv, wv[E_];
    if (isf32) {
      xv = (double)((const float*)xr)[(size_t)token * D_ + k];
#pragma unroll
      for (int e2 = 0; e2 < E_; ++e2) wv[e2] = (double)((const float*)gwr)[e2 * D_ + k];
    } else {
      xv = (double)bf2f(((const unsigned short*)xr)[(size_t)token * D_ + k]);
#pragma unroll
      for (int e2 = 0; e2 < E_; ++e2) wv[e2] = (double)bf2f(((const unsigned short*)gwr)[e2 * D_ + k]);
    }
#pragma unroll
    for (int e2 = 0; e2 < E_; ++e2) acc[e2] += xv * wv[e2];
  }
#pragma unroll
  for (int e2 = 0; e2 < E_; ++e2) {
#pragma unroll
    for (int off = 1; off < 64; off <<= 1) acc[e2] += __shfl_xor(acc[e2], off);
  }
  if (lane < E_) {
    double mx = acc[0];
#pragma unroll
    for (int e2 = 1; e2 < E_; ++e2) mx = acc[e2] > mx ? acc[e2] : mx;
    double ssum = 0.0;
#pragma unroll
    for (int e2 = 0; e2 < E_; ++e2) ssum += exp(acc[e2] - mx);
    double p = exp(acc[lane] - mx) / ssum;
    int b = token >> 12, s = token & (S_ - 1);
    aff[((size_t)b * E_ + lane) * S_ + s] = p;
  }
}

// ---------------- 2. top-1024-of-4096 radix select per (b,e) ----------------
__global__ __launch_bounds__(256) void topk_sel_k(
    const double* __restrict__ aff, int* __restrict__ sel_idx, float* __restrict__ sel_gate) {
  __shared__ unsigned long long keys[4096];
  __shared__ unsigned int hist[256];
  __shared__ unsigned int bcast[3];
  const int g = blockIdx.x, t = threadIdx.x;
  const int e = g >> 2, b = g & 3;  // expert-major group order
  const double* ap = aff + ((size_t)b * E_ + e) * S_;
  for (int j = 0; j < 16; ++j) {
    int i = t + 256 * j;
    keys[i] = __double_as_longlong(ap[i]);  // positive doubles: uint64 order == value order
  }
  __syncthreads();
  unsigned long long prefix = 0ull;
  int remaining = KCAP;
  for (int p = 7; p >= 0; --p) {
    hist[t] = 0;
    __syncthreads();
    unsigned long long mask_hi = (p == 7) ? 0ull : (~0ull << ((p + 1) * 8));
    for (int j = 0; j < 16; ++j) {
      unsigned long long key = keys[t + 256 * j];
      if ((key & mask_hi) == prefix)
        atomicAdd(&hist[(unsigned)(key >> (p * 8)) & 255u], 1u);
    }
    __syncthreads();
    if (t == 0) {
      unsigned cum = 0; int bsel = 0;
      for (int v = 255; v >= 0; --v) {
        unsigned cc = hist[v];
        if (cum + cc >= (unsigned)remaining) { bsel = v; break; }
        cum += cc;
      }
      bcast[0] = (unsigned)bsel; bcast[1] = cum;
    }
    __syncthreads();
    prefix |= ((unsigned long long)bcast[0]) << (p * 8);
    remaining -= (int)bcast[1];
    __syncthreads();
  }
  if (t == 0) bcast[2] = 0;
  __syncthreads();
  const unsigned long long T = prefix;  // 1024th-largest key
  for (int j = 0; j < 16; ++j) {
    int i = t + 256 * j;
    unsigned long long key = keys[i];
    if (key > T) {
      unsigned pos = atomicAdd(&bcast[2], 1u);
      sel_idx[g * KCAP + pos] = i;
      sel_gate[g * KCAP + pos] = (float)__longlong_as_double(key);
    }
  }
  __syncthreads();
  for (int j = 0; j < 16; ++j) {
    int i = t + 256 * j;
    unsigned long long key = keys[i];
    if (key == T) {
      unsigned pos = atomicAdd(&bcast[2], 1u);
      if (pos < KCAP) {
        sel_idx[g * KCAP + pos] = i;
        sel_gate[g * KCAP + pos] = (float)__longlong_as_double(key);
      }
    }
  }
}

// ---------------- 3. fused gate/up GEMM + SiLU -> h (bf16) ----------------
// BM=256, BN=128 (per matrix), BK=32, 512 thr / 8 waves (2Mx4N), ring-4 LDS.
// LDS slot (32KB = 16384 shorts): A(256x32 k-major chunks) at 0..8191,
// G(128x32) at 8192..12287, U at 12288..16383. Chunk (row,kq) of A lives at
// short-offset (kq*256+row)*8; of G/U at (kq*128+row)*8. Staged so LDS is
// linear in thread index (global source carries the permutation).
__global__ __launch_bounds__(512, 2) void moe_gemm1(
    const unsigned short* __restrict__ x, const unsigned short* __restrict__ w_gate,
    const unsigned short* __restrict__ w_up, const int* __restrict__ sel_idx,
    unsigned short* __restrict__ hbuf, int chunk_start) {
  __shared__ __align__(16) unsigned short lds[4 * 16384];  // 128 KiB
  const int gc = blockIdx.z;
  const int g = chunk_start + gc;
  const int e = g >> 2, b = g & 3;
  // XCD-chunked bijective swizzle: 128 blocks/group, 128%8==0
  const int lid = blockIdx.x;
  const int swz = (lid & 7) * 16 + (lid >> 3);
  const int m0 = (swz & 3) * 256, n0 = (swz >> 2) * 128;
  const int t = threadIdx.x;
  const int wave = t >> 6, lane = t & 63;
  const int wm = wave >> 2, wn = wave & 3;          // 2 x 4 waves
  const int row16 = lane & 15, quad = lane >> 4;

  // staging source pointers (k-major chunk permutation)
  const int atok = sel_idx[g * KCAP + m0 + (t & 255)] & (S_ - 1);
  const unsigned short* gA = x + ((size_t)b * S_ + atok) * D_ + (t >> 8) * 8;
  const unsigned short* gG = w_gate + ((size_t)e * I_ + n0 + (t & 127)) * D_ + (t >> 7) * 8;
  const unsigned short* gU = w_up + ((size_t)e * I_ + n0 + (t & 127)) * D_ + (t >> 7) * 8;

  floatx4 accg[8][2], accu[8][2];
#pragma unroll
  for (int m = 0; m < 8; ++m)
#pragma unroll
    for (int n = 0; n < 2; ++n) {
      accg[m][n] = (floatx4){0.f, 0.f, 0.f, 0.f};
      accu[m][n] = (floatx4){0.f, 0.f, 0.f, 0.f};
    }

#define STG1(KT, SL) do {                                   \
    unsigned short* sb_ = lds + (SL) * 16384;               \
    const int k0_ = (KT) * 32;                              \
    GLD16(gA + k0_,      sb_ + wave * 512);                 \
    GLD16(gA + k0_ + 16, sb_ + 4096 + wave * 512);          \
    GLD16(gG + k0_,      sb_ + 8192 + wave * 512);          \
    GLD16(gU + k0_,      sb_ + 12288 + wave * 512);         \
  } while (0)

#define COMP1(SL) do {                                                              \
    const unsigned short* sb_ = lds + (SL) * 16384;                                 \
    bf16x8 af[8], gf[2], uf[2];                                                     \
    _Pragma("unroll")                                                               \
    for (int m = 0; m < 8; ++m)                                                     \
      af[m] = *(const bf16x8*)(sb_ + (quad * 256 + wm * 128 + m * 16 + row16) * 8); \
    _Pragma("unroll")                                                               \
    for (int n = 0; n < 2; ++n) {                                                   \
      gf[n] = *(const bf16x8*)(sb_ + 8192 + (quad * 128 + wn * 32 + n * 16 + row16) * 8);  \
      uf[n] = *(const bf16x8*)(sb_ + 12288 + (quad * 128 + wn * 32 + n * 16 + row16) * 8); \
    }                                                                               \
    __builtin_amdgcn_s_setprio(1);                                                  \
    _Pragma("unroll")                                                               \
    for (int m = 0; m < 8; ++m)                                                     \
      _Pragma("unroll")                                                             \
      for (int n = 0; n < 2; ++n) {                                                 \
        accg[m][n] = __builtin_amdgcn_mfma_f32_16x16x32_bf16(af[m], gf[n], accg[m][n], 0, 0, 0); \
        accu[m][n] = __builtin_amdgcn_mfma_f32_16x16x32_bf16(af[m], uf[n], accu[m][n], 0, 0, 0); \
      }                                                                             \
    __builtin_amdgcn_s_setprio(0);                                                  \
  } while (0)

  // prologue: 3 tiles in flight (12 loads); fences keep GLD program order
  STG1(0, 0); CFENCE(); STG1(1, 1); CFENCE(); STG1(2, 2);
  // main: D/32 = 32 K-tiles. vmcnt(8) == "my tile-kt loads landed, 2 tiles in flight"
#pragma unroll 4
  for (int kt = 0; kt < 28; ++kt) {
    WAITV(8); RAW_BAR();
    STG1(kt + 3, (kt + 3) & 3);
    COMP1(kt & 3);
  }
  { WAITV(8); RAW_BAR(); STG1(31, 3); COMP1(0); }  // kt=28
  { WAITV(8); RAW_BAR(); COMP1(1); }               // kt=29
  { WAITV(4); RAW_BAR(); COMP1(2); }               // kt=30
  { WAITV(0); RAW_BAR(); COMP1(3); }               // kt=31
#undef STG1
#undef COMP1

  unsigned short* hb = hbuf + (size_t)gc * ((size_t)KCAP * I_);
#pragma unroll
  for (int m = 0; m < 8; ++m)
#pragma unroll
    for (int n = 0; n < 2; ++n)
#pragma unroll
      for (int r4 = 0; r4 < 4; ++r4) {
        int mm = m0 + wm * 128 + m * 16 + quad * 4 + r4;
        int nn = n0 + wn * 32 + n * 16 + row16;
        float gv = accg[m][n][r4], uv = accu[m][n][r4];
        float hv = gv / (1.f + __expf(-gv)) * uv;  // silu(g)*u
        hb[(size_t)mm * I_ + nn] = f2bf(hv);
      }
}

// ---------------- 4. down GEMM + gated fp32 atomic scatter ----------------
// BM=256, BN=256, BK=32, same ring-4 pipeline. Slot: A at 0..8191, B at 8192..16383.
__global__ __launch_bounds__(512, 2) void moe_gemm2(
    const unsigned short* __restrict__ hbuf, const unsigned short* __restrict__ w_down,
    const int* __restrict__ sel_idx, const float* __restrict__ sel_gate,
    float* __restrict__ acc_out, int chunk_start) {
  __shared__ __align__(16) unsigned short lds[4 * 16384];  // 128 KiB
  __shared__ int stok[256];
  __shared__ float sgt[256];
  const int gc = blockIdx.z;
  const int g = chunk_start + gc;
  const int e = g >> 2, b = g & 3;
  const int m0 = (blockIdx.x & 3) * 256, n0 = (blockIdx.x >> 2) * 256;  // linear: m-locality per XCD
  const int t = threadIdx.x;
  const int wave = t >> 6, lane = t & 63;
  const int wm = wave >> 2, wn = wave & 3;
  const int row16 = lane & 15, quad = lane >> 4;

  if (t < 256) {
    stok[t] = sel_idx[g * KCAP + m0 + t] & (S_ - 1);
    sgt[t] = sel_gate[g * KCAP + m0 + t];
  }

  const unsigned short* gA = hbuf + (size_t)gc * ((size_t)KCAP * I_) +
                             (size_t)(m0 + (t & 255)) * I_ + (t >> 8) * 8;
  const unsigned short* gB = w_down + ((size_t)e * D_ + n0 + (t & 255)) * I_ + (t >> 8) * 8;

  floatx4 accf[8][4];
#pragma unroll
  for (int m = 0; m < 8; ++m)
#pragma unroll
    for (int n = 0; n < 4; ++n) accf[m][n] = (floatx4){0.f, 0.f, 0.f, 0.f};

#define STG2(KT, SL) do {                                   \
    unsigned short* sb_ = lds + (SL) * 16384;               \
    const int k0_ = (KT) * 32;                              \
    GLD16(gA + k0_,      sb_ + wave * 512);                 \
    GLD16(gA + k0_ + 16, sb_ + 4096 + wave * 512);          \
    GLD16(gB + k0_,      sb_ + 8192 + wave * 512);          \
    GLD16(gB + k0_ + 16, sb_ + 12288 + wave * 512);         \
  } while (0)

#define COMP2(SL) do {                                                              \
    const unsigned short* sb_ = lds + (SL) * 16384;                                 \
    bf16x8 af[8], bf[4];                                                            \
    _Pragma("unroll")                                                               \
    for (int m = 0; m < 8; ++m)                                                     \
      af[m] = *(const bf16x8*)(sb_ + (quad * 256 + wm * 128 + m * 16 + row16) * 8); \
    _Pragma("unroll")                                                               \
    for (int n = 0; n < 4; ++n)                                                     \
      bf[n] = *(const bf16x8*)(sb_ + 8192 + (quad * 256 + wn * 64 + n * 16 + row16) * 8); \
    __builtin_amdgcn_s_setprio(1);                                                  \
    _Pragma("unroll")                                                               \
    for (int m = 0; m < 8; ++m)                                                     \
      _Pragma("unroll")                                                             \
      for (int n = 0; n < 4; ++n)                                                   \
        accf[m][n] = __builtin_amdgcn_mfma_f32_16x16x32_bf16(af[m], bf[n], accf[m][n], 0, 0, 0); \
    __builtin_amdgcn_s_setprio(0);                                                  \
  } while (0)

  STG2(0, 0); CFENCE(); STG2(1, 1); CFENCE(); STG2(2, 2);
  // K = I_ = 4096 -> NT = 128 K-tiles
#pragma unroll 4
  for (int kt = 0; kt < 124; ++kt) {
    WAITV(8); RAW_BAR();
    STG2(kt + 3, (kt + 3) & 3);
    COMP2(kt & 3);
  }
  { WAITV(8); RAW_BAR(); STG2(127, 3); COMP2(0); }  // kt=124
  { WAITV(8); RAW_BAR(); COMP2(1); }                // kt=125
  { WAITV(4); RAW_BAR(); COMP2(2); }                // kt=126
  { WAITV(0); RAW_BAR(); COMP2(3); }                // kt=127
#undef STG2
#undef COMP2

#pragma unroll
  for (int m = 0; m < 8; ++m)
#pragma unroll
    for (int r4 = 0; r4 < 4; ++r4) {
      int mloc = wm * 128 + m * 16 + quad * 4 + r4;
      int tok = stok[mloc];
      float gt = sgt[mloc];
      float* basep = acc_out + ((size_t)b * S_ + tok) * D_ + n0 + wn * 64 + row16;
#pragma unroll
      for (int n = 0; n < 4; ++n) unsafeAtomicAdd(basep + n * 16, accf[m][n][r4] * gt);
    }
}

// ---------------- 5. fp32 accumulator -> output (dtype per flag) ----------------
__global__ __launch_bounds__(256) void conv_out_k(const float* __restrict__ acc,
                                                  void* __restrict__ out,
                                                  const int* __restrict__ flag) {
  const int isf32 = *flag;
  size_t i = ((size_t)blockIdx.x * 256 + threadIdx.x) * 4;
  float4 v = *(const float4*)(acc + i);
  if (isf32) {
    *(float4*)((float*)out + i) = v;
  } else {
    ushort4 o;
    o.x = f2bf(v.x); o.y = f2bf(v.y); o.z = f2bf(v.z); o.w = f2bf(v.w);
    *(ushort4*)((unsigned short*)out + i) = o;
  }
}

extern "C" void kernel_launch(void* const* d_in, const int* in_sizes, int n_in,
                              void* d_out, int out_size, void* d_ws, size_t ws_size,
                              hipStream_t stream) {
  const void* x_raw = d_in[0];
  const void* gate_w_raw = d_in[1];
  const void* w_gate_raw = d_in[2];
  const void* w_up_raw = d_in[3];
  const void* w_down_raw = d_in[4];

  char* ws = (char*)d_ws;
  size_t off = 0;
  auto alloc = [&](size_t bytes) { char* p = ws + off; off += (bytes + 255) & ~(size_t)255; return p; };
  float* acc = (float*)alloc((size_t)B_ * S_ * D_ * 4);          // 64 MB
  double* aff = (double*)alloc((size_t)B_ * E_ * S_ * 8);        // 1 MB
  int* sel_idx = (int*)alloc((size_t)NGROUPS * KCAP * 4);        // 128 KB
  float* sel_gate = (float*)alloc((size_t)NGROUPS * KCAP * 4);   // 128 KB
  int* flag = (int*)alloc(256);
  unsigned short* xb = (unsigned short*)alloc((size_t)B_ * S_ * D_ * 2);    // 33.5 MB
  unsigned short* wgb = (unsigned short*)alloc((size_t)E_ * I_ * D_ * 2);   // 67 MB
  unsigned short* wub = (unsigned short*)alloc((size_t)E_ * I_ * D_ * 2);   // 67 MB
  unsigned short* wdb = (unsigned short*)alloc((size_t)E_ * D_ * I_ * 2);   // 67 MB
  const size_t fixedBytes = off;
  const size_t hPerGroup = (size_t)KCAP * I_ * 2;  // 8 MB bf16
  int gch = 32;
  while (gch > 1 && fixedBytes + (size_t)gch * hPerGroup > ws_size) gch >>= 1;
  unsigned short* hbuf = (unsigned short*)(ws + fixedBytes);

  hipMemsetAsync(acc, 0, (size_t)B_ * S_ * D_ * 4, stream);
  hipMemsetAsync(sel_idx, 0, (size_t)NGROUPS * KCAP * 8, stream);

  probe_dtype_k<<<dim3(1), dim3(256), 0, stream>>>((const unsigned short*)x_raw, flag);
  conv_in_k<<<dim3((int)((size_t)B_ * S_ * D_ / 2048)), dim3(256), 0, stream>>>(x_raw, xb, flag);
  conv_in_k<<<dim3((int)((size_t)E_ * I_ * D_ / 2048)), dim3(256), 0, stream>>>(w_gate_raw, wgb, flag);
  conv_in_k<<<dim3((int)((size_t)E_ * I_ * D_ / 2048)), dim3(256), 0, stream>>>(w_up_raw, wub, flag);
  conv_in_k<<<dim3((int)((size_t)E_ * D_ * I_ / 2048)), dim3(256), 0, stream>>>(w_down_raw, wdb, flag);

  gate_softmax_k<<<dim3(B_ * S_ / 4), dim3(256), 0, stream>>>(x_raw, gate_w_raw, flag, aff);
  topk_sel_k<<<dim3(NGROUPS), dim3(256), 0, stream>>>(aff, sel_idx, sel_gate);
  for (int c0 = 0; c0 < NGROUPS; c0 += gch) {
    int gcur = (NGROUPS - c0) < gch ? (NGROUPS - c0) : gch;
    moe_gemm1<<<dim3(128, 1, gcur), dim3(512), 0, stream>>>(
        xb, wgb, wub, sel_idx, hbuf, c0);
    moe_gemm2<<<dim3(16, 1, gcur), dim3(512), 0, stream>>>(
        hbuf, wdb, sel_idx, sel_gate, acc, c0);
  }
  conv_out_k<<<dim3((int)((size_t)B_ * S_ * D_ / 4 / 256)), dim3(256), 0, stream>>>(acc, d_out, flag);
}

// Round 4
// 1914.841 us; speedup vs baseline: 1.0190x; 1.0190x over previous
//
#include <hip/hip_runtime.h>
#include <hip/hip_bf16.h>

// Expert-choice MoE, MI355X. B=4,S=4096,D=1024,E=8,I=4096, k=1024 per (b,e).
// R7: m201-style phase discipline on R6's ring-4 pipeline. Per K-step (BK=32),
// 2 phases: {ds_read subtile; 2x global_load_lds; s_barrier; lgkmcnt(0)+
// sched_barrier; setprio(1); 16 MFMA; setprio(0); s_barrier}. vmcnt(8) once
// per K-step (3 K-steps in flight, never drained in-loop). Conflict-free
// k-major chunk LDS layout (R6, measured 0 conflicts). XCD swizzle kept.

#define B_ 4
#define S_ 4096
#define D_ 1024
#define E_ 8
#define I_ 4096
#define KCAP 1024
#define NGROUPS 32

typedef __bf16 bf16x8 __attribute__((ext_vector_type(8)));
typedef float floatx4 __attribute__((ext_vector_type(4)));

#define GLD16(gptr, lptr)                                          \
  __builtin_amdgcn_global_load_lds(                                \
      (const __attribute__((address_space(1))) void*)(gptr),       \
      (__attribute__((address_space(3))) void*)(lptr), 16, 0, 0)

#define WAITV(N) asm volatile("s_waitcnt vmcnt(" #N ")" ::: "memory")
#define LGKM0() do { asm volatile("s_waitcnt lgkmcnt(0)" ::: "memory"); \
                     __builtin_amdgcn_sched_barrier(0); } while (0)
#define RAW_BAR() __builtin_amdgcn_s_barrier()
#define CFENCE() asm volatile("" ::: "memory")
#define MFMA_BF16(A, Bb, C) __builtin_amdgcn_mfma_f32_16x16x32_bf16((A), (Bb), (C), 0, 0, 0)

__device__ __forceinline__ float bf2f(unsigned short h) {
  union { unsigned int u; float f; } v; v.u = ((unsigned int)h) << 16; return v.f;
}
__device__ __forceinline__ unsigned short f2bf(float f) {
  union { float f; unsigned int u; } v; v.f = f;
  unsigned int r = (v.u + 0x7fffu + ((v.u >> 16) & 1u)) >> 16;
  return (unsigned short)r;
}

// ---------------- 0. dtype probe ----------------
__global__ __launch_bounds__(256) void probe_dtype_k(const unsigned short* __restrict__ xr,
                                                     int* __restrict__ flag) {
  __shared__ unsigned int cnt;
  if (threadIdx.x == 0) cnt = 0;
  __syncthreads();
  unsigned int local = 0;
  for (int j = 0; j < 16; ++j) {
    int k = threadIdx.x * 16 + j;
    unsigned short u = xr[2 * k];
    unsigned int expf = (u >> 7) & 0xFF;
    if (expf >= 0x90 && expf != 0xFF) local++;
    if (expf == 0xFF) local++;
  }
  atomicAdd(&cnt, local);
  __syncthreads();
  if (threadIdx.x == 0) *flag = (cnt > 256u) ? 1 : 0;
}

// ---------------- 0b. convert input -> bf16 ----------------
__global__ __launch_bounds__(256) void conv_in_k(const void* __restrict__ src,
                                                 unsigned short* __restrict__ dst,
                                                 const int* __restrict__ flag) {
  const int isf32 = *flag;
  size_t i = ((size_t)blockIdx.x * 256 + threadIdx.x) * 8;
  if (isf32) {
    const float* s = (const float*)src;
    float4 a = *(const float4*)(s + i);
    float4 b = *(const float4*)(s + i + 4);
    ushort4 o0, o1;
    o0.x = f2bf(a.x); o0.y = f2bf(a.y); o0.z = f2bf(a.z); o0.w = f2bf(a.w);
    o1.x = f2bf(b.x); o1.y = f2bf(b.y); o1.z = f2bf(b.z); o1.w = f2bf(b.w);
    *(ushort4*)(dst + i) = o0;
    *(ushort4*)(dst + i + 4) = o1;
  } else {
    const uint4* s = (const uint4*)src;
    *(uint4*)(dst + i) = s[i / 8];
  }
}

// ---------------- 1. gate logits + softmax ----------------
__global__ __launch_bounds__(256) void gate_softmax_k(
    const void* __restrict__ xr, const void* __restrict__ gwr,
    const int* __restrict__ flag, double* __restrict__ aff) {
  const int isf32 = *flag;
  const int wave = threadIdx.x >> 6, lane = threadIdx.x & 63;
  const int token = blockIdx.x * 4 + wave;
  double acc[E_];
#pragma unroll
  for (int e2 = 0; e2 < E_; ++e2) acc[e2] = 0.0;
  for (int j = 0; j < 16; ++j) {
    int k = lane + 64 * j;
    double xv, wv[E_];
    if (isf32) {
      xv = (double)((const float*)xr)[(size_t)token * D_ + k];
#pragma unroll
      for (int e2 = 0; e2 < E_; ++e2) wv[e2] = (double)((const float*)gwr)[e2 * D_ + k];
    } else {
      xv = (double)bf2f(((const unsigned short*)xr)[(size_t)token * D_ + k]);
#pragma unroll
      for (int e2 = 0; e2 < E_; ++e2) wv[e2] = (double)bf2f(((const unsigned short*)gwr)[e2 * D_ + k]);
    }
#pragma unroll
    for (int e2 = 0; e2 < E_; ++e2) acc[e2] += xv * wv[e2];
  }
#pragma unroll
  for (int e2 = 0; e2 < E_; ++e2) {
#pragma unroll
    for (int off = 1; off < 64; off <<= 1) acc[e2] += __shfl_xor(acc[e2], off);
  }
  if (lane < E_) {
    double mx = acc[0];
#pragma unroll
    for (int e2 = 1; e2 < E_; ++e2) mx = acc[e2] > mx ? acc[e2] : mx;
    double ssum = 0.0;
#pragma unroll
    for (int e2 = 0; e2 < E_; ++e2) ssum += exp(acc[e2] - mx);
    double p = exp(acc[lane] - mx) / ssum;
    int b = token >> 12, s = token & (S_ - 1);
    aff[((size_t)b * E_ + lane) * S_ + s] = p;
  }
}

// ---------------- 2. top-1024-of-4096 radix select ----------------
__global__ __launch_bounds__(256) void topk_sel_k(
    const double* __restrict__ aff, int* __restrict__ sel_idx, float* __restrict__ sel_gate) {
  __shared__ unsigned long long keys[4096];
  __shared__ unsigned int hist[256];
  __shared__ unsigned int bcast[3];
  const int g = blockIdx.x, t = threadIdx.x;
  const int e = g >> 2, b = g & 3;
  const double* ap = aff + ((size_t)b * E_ + e) * S_;
  for (int j = 0; j < 16; ++j) {
    int i = t + 256 * j;
    keys[i] = __double_as_longlong(ap[i]);
  }
  __syncthreads();
  unsigned long long prefix = 0ull;
  int remaining = KCAP;
  for (int p = 7; p >= 0; --p) {
    hist[t] = 0;
    __syncthreads();
    unsigned long long mask_hi = (p == 7) ? 0ull : (~0ull << ((p + 1) * 8));
    for (int j = 0; j < 16; ++j) {
      unsigned long long key = keys[t + 256 * j];
      if ((key & mask_hi) == prefix)
        atomicAdd(&hist[(unsigned)(key >> (p * 8)) & 255u], 1u);
    }
    __syncthreads();
    if (t == 0) {
      unsigned cum = 0; int bsel = 0;
      for (int v = 255; v >= 0; --v) {
        unsigned cc = hist[v];
        if (cum + cc >= (unsigned)remaining) { bsel = v; break; }
        cum += cc;
      }
      bcast[0] = (unsigned)bsel; bcast[1] = cum;
    }
    __syncthreads();
    prefix |= ((unsigned long long)bcast[0]) << (p * 8);
    remaining -= (int)bcast[1];
    __syncthreads();
  }
  if (t == 0) bcast[2] = 0;
  __syncthreads();
  const unsigned long long T = prefix;
  for (int j = 0; j < 16; ++j) {
    int i = t + 256 * j;
    unsigned long long key = keys[i];
    if (key > T) {
      unsigned pos = atomicAdd(&bcast[2], 1u);
      sel_idx[g * KCAP + pos] = i;
      sel_gate[g * KCAP + pos] = (float)__longlong_as_double(key);
    }
  }
  __syncthreads();
  for (int j = 0; j < 16; ++j) {
    int i = t + 256 * j;
    unsigned long long key = keys[i];
    if (key == T) {
      unsigned pos = atomicAdd(&bcast[2], 1u);
      if (pos < KCAP) {
        sel_idx[g * KCAP + pos] = i;
        sel_gate[g * KCAP + pos] = (float)__longlong_as_double(key);
      }
    }
  }
}

// ---------------- 3. fused gate/up GEMM + SiLU -> h (bf16) ----------------
// BM=256, BN=128 per matrix, BK=32, ring-4 x 32KB slots (A 16K | G 8K | U 8K),
// 512 thr / 8 waves (2Mx4N). K-step = 2 phases, m201 discipline.
__global__ __launch_bounds__(512, 1) void moe_gemm1(
    const unsigned short* __restrict__ x, const unsigned short* __restrict__ w_gate,
    const unsigned short* __restrict__ w_up, const int* __restrict__ sel_idx,
    unsigned short* __restrict__ hbuf, int chunk_start) {
  __shared__ __align__(16) unsigned short lds[4 * 16384];  // 128 KiB
  const int gc = blockIdx.z;
  const int g = chunk_start + gc;
  const int e = g >> 2, b = g & 3;
  const int lid = blockIdx.x;
  const int swz = (lid & 7) * 16 + (lid >> 3);      // bijective, 128 % 8 == 0
  const int m0 = (swz & 3) * 256, n0 = (swz >> 2) * 128;
  const int t = threadIdx.x;
  const int wave = t >> 6, lane = t & 63;
  const int wm = wave >> 2, wn = wave & 3;
  const int row16 = lane & 15, quad = lane >> 4;

  const int tokA = sel_idx[g * KCAP + m0 + (t & 255)] & (S_ - 1);
  const unsigned short* pA = x + ((size_t)b * S_ + tokA) * D_ + (t >> 8) * 8;
  const unsigned short* pG = w_gate + ((size_t)e * I_ + n0 + (t & 127)) * D_ + (t >> 7) * 8;
  const unsigned short* pU = w_up + ((size_t)e * I_ + n0 + (t & 127)) * D_ + (t >> 7) * 8;

  floatx4 accg[8][2], accu[8][2];
#pragma unroll
  for (int m = 0; m < 8; ++m)
#pragma unroll
    for (int n = 0; n < 2; ++n) {
      accg[m][n] = (floatx4){0.f, 0.f, 0.f, 0.f};
      accu[m][n] = (floatx4){0.f, 0.f, 0.f, 0.f};
    }
  bf16x8 af[4], gf[2], uf[2];

#define STG1(KT, SL) do { unsigned short* sb_ = lds + (SL) * 16384;  \
    const int k0_ = (KT) * 32;                                       \
    GLD16(pA + k0_,      sb_ + wave * 512);                          \
    GLD16(pA + k0_ + 16, sb_ + 4096 + wave * 512);                   \
    GLD16(pG + k0_,      sb_ + 8192 + wave * 512);                   \
    GLD16(pU + k0_,      sb_ + 12288 + wave * 512); } while (0)

#define PHA1(CS, SS, KS) do {                                                        \
    const unsigned short* cb_ = lds + (CS) * 16384;                                  \
    unsigned short* sb_ = lds + (SS) * 16384;                                        \
    _Pragma("unroll")                                                                \
    for (int m = 0; m < 4; ++m)                                                      \
      af[m] = *(const bf16x8*)(cb_ + (quad * 256 + wm * 128 + m * 16 + row16) * 8);  \
    _Pragma("unroll")                                                                \
    for (int n = 0; n < 2; ++n) {                                                    \
      gf[n] = *(const bf16x8*)(cb_ + 8192 + (quad * 128 + wn * 32 + n * 16 + row16) * 8);  \
      uf[n] = *(const bf16x8*)(cb_ + 12288 + (quad * 128 + wn * 32 + n * 16 + row16) * 8); \
    }                                                                                \
    GLD16(pA + (KS) * 32,      sb_ + wave * 512);                                    \
    GLD16(pA + (KS) * 32 + 16, sb_ + 4096 + wave * 512);                             \
    RAW_BAR();                                                                       \
    LGKM0();                                                                         \
    __builtin_amdgcn_s_setprio(1);                                                   \
    _Pragma("unroll")                                                                \
    for (int m = 0; m < 4; ++m)                                                      \
      _Pragma("unroll")                                                              \
      for (int n = 0; n < 2; ++n) {                                                  \
        accg[m][n] = MFMA_BF16(af[m], gf[n], accg[m][n]);                            \
        accu[m][n] = MFMA_BF16(af[m], uf[n], accu[m][n]);                            \
      }                                                                              \
    __builtin_amdgcn_s_setprio(0);                                                   \
    RAW_BAR(); } while (0)

#define PHB1(CS, SS, KS) do {                                                        \
    const unsigned short* cb_ = lds + (CS) * 16384;                                  \
    unsigned short* sb_ = lds + (SS) * 16384;                                        \
    _Pragma("unroll")                                                                \
    for (int m = 0; m < 4; ++m)                                                      \
      af[m] = *(const bf16x8*)(cb_ + (quad * 256 + wm * 128 + (m + 4) * 16 + row16) * 8); \
    GLD16(pG + (KS) * 32, sb_ + 8192 + wave * 512);                                  \
    GLD16(pU + (KS) * 32, sb_ + 12288 + wave * 512);                                 \
    WAITV(8);                                                                        \
    RAW_BAR();                                                                       \
    LGKM0();                                                                         \
    __builtin_amdgcn_s_setprio(1);                                                   \
    _Pragma("unroll")                                                                \
    for (int m = 0; m < 4; ++m)                                                      \
      _Pragma("unroll")                                                              \
      for (int n = 0; n < 2; ++n) {                                                  \
        accg[m + 4][n] = MFMA_BF16(af[m], gf[n], accg[m + 4][n]);                    \
        accu[m + 4][n] = MFMA_BF16(af[m], uf[n], accu[m + 4][n]);                    \
      }                                                                              \
    __builtin_amdgcn_s_setprio(0);                                                   \
    RAW_BAR(); } while (0)

  STG1(0, 0); CFENCE(); STG1(1, 1); CFENCE(); STG1(2, 2);
  WAITV(8); RAW_BAR();   // K-step 0 landed everywhere

  for (int kt = 0; kt < 32; kt += 4) {
    int ks;
    ks = kt + 3 > 31 ? 31 : kt + 3;  PHA1(0, 3, ks); PHB1(0, 3, ks);
    ks = kt + 4 > 31 ? 31 : kt + 4;  PHA1(1, 0, ks); PHB1(1, 0, ks);
    ks = kt + 5 > 31 ? 31 : kt + 5;  PHA1(2, 1, ks); PHB1(2, 1, ks);
    ks = kt + 6 > 31 ? 31 : kt + 6;  PHA1(3, 2, ks); PHB1(3, 2, ks);
  }
  WAITV(0);  // no DMA outlives the workgroup
#undef STG1
#undef PHA1
#undef PHB1

  unsigned short* hb = hbuf + (size_t)gc * ((size_t)KCAP * I_);
#pragma unroll
  for (int m = 0; m < 8; ++m)
#pragma unroll
    for (int n = 0; n < 2; ++n)
#pragma unroll
      for (int r4 = 0; r4 < 4; ++r4) {
        int mm = m0 + wm * 128 + m * 16 + quad * 4 + r4;
        int nn = n0 + wn * 32 + n * 16 + row16;
        float gv = accg[m][n][r4], uv = accu[m][n][r4];
        float hv = gv / (1.f + __expf(-gv)) * uv;  // silu(g)*u
        hb[(size_t)mm * I_ + nn] = f2bf(hv);
      }
}

// ---------------- 4. down GEMM + gated fp32 atomic scatter ----------------
// BM=256, BN=256, BK=32, ring-4 x 32KB slots (A 16K | B 16K), same discipline.
__global__ __launch_bounds__(512, 1) void moe_gemm2(
    const unsigned short* __restrict__ hbuf, const unsigned short* __restrict__ w_down,
    const int* __restrict__ sel_idx, const float* __restrict__ sel_gate,
    float* __restrict__ acc_out, int chunk_start) {
  __shared__ __align__(16) unsigned short lds[4 * 16384];  // 128 KiB
  __shared__ int stok[256];
  __shared__ float sgt[256];
  const int gc = blockIdx.z;
  const int g = chunk_start + gc;
  const int e = g >> 2, b = g & 3;
  const int m0 = (blockIdx.x & 3) * 256, n0 = (blockIdx.x >> 2) * 256;
  const int t = threadIdx.x;
  const int wave = t >> 6, lane = t & 63;
  const int wm = wave >> 2, wn = wave & 3;
  const int row16 = lane & 15, quad = lane >> 4;

  if (t < 256) {
    stok[t] = sel_idx[g * KCAP + m0 + t] & (S_ - 1);
    sgt[t] = sel_gate[g * KCAP + m0 + t];
  }

  const unsigned short* pA = hbuf + (size_t)gc * ((size_t)KCAP * I_) +
                             (size_t)(m0 + (t & 255)) * I_ + (t >> 8) * 8;
  const unsigned short* pB = w_down + ((size_t)e * D_ + n0 + (t & 255)) * I_ + (t >> 8) * 8;

  floatx4 accf[8][4];
#pragma unroll
  for (int m = 0; m < 8; ++m)
#pragma unroll
    for (int n = 0; n < 4; ++n) accf[m][n] = (floatx4){0.f, 0.f, 0.f, 0.f};
  bf16x8 af[4], bf[4];

#define STG2(KT, SL) do { unsigned short* sb_ = lds + (SL) * 16384;  \
    const int k0_ = (KT) * 32;                                       \
    GLD16(pA + k0_,      sb_ + wave * 512);                          \
    GLD16(pA + k0_ + 16, sb_ + 4096 + wave * 512);                   \
    GLD16(pB + k0_,      sb_ + 8192 + wave * 512);                   \
    GLD16(pB + k0_ + 16, sb_ + 12288 + wave * 512); } while (0)

#define PHA2(CS, SS, KS) do {                                                        \
    const unsigned short* cb_ = lds + (CS) * 16384;                                  \
    unsigned short* sb_ = lds + (SS) * 16384;                                        \
    _Pragma("unroll")                                                                \
    for (int m = 0; m < 4; ++m)                                                      \
      af[m] = *(const bf16x8*)(cb_ + (quad * 256 + wm * 128 + m * 16 + row16) * 8);  \
    _Pragma("unroll")                                                                \
    for (int n = 0; n < 4; ++n)                                                      \
      bf[n] = *(const bf16x8*)(cb_ + 8192 + (quad * 256 + wn * 64 + n * 16 + row16) * 8); \
    GLD16(pA + (KS) * 32,      sb_ + wave * 512);                                    \
    GLD16(pA + (KS) * 32 + 16, sb_ + 4096 + wave * 512);                             \
    RAW_BAR();                                                                       \
    LGKM0();                                                                         \
    __builtin_amdgcn_s_setprio(1);                                                   \
    _Pragma("unroll")                                                                \
    for (int m = 0; m < 4; ++m)                                                      \
      _Pragma("unroll")                                                              \
      for (int n = 0; n < 4; ++n)                                                    \
        accf[m][n] = MFMA_BF16(af[m], bf[n], accf[m][n]);                            \
    __builtin_amdgcn_s_setprio(0);                                                   \
    RAW_BAR(); } while (0)

#define PHB2(CS, SS, KS) do {                                                        \
    const unsigned short* cb_ = lds + (CS) * 16384;                                  \
    unsigned short* sb_ = lds + (SS) * 16384;                                        \
    _Pragma("unroll")                                                                \
    for (int m = 0; m < 4; ++m)                                                      \
      af[m] = *(const bf16x8*)(cb_ + (quad * 256 + wm * 128 + (m + 4) * 16 + row16) * 8); \
    GLD16(pB + (KS) * 32,      sb_ + 8192 + wave * 512);                             \
    GLD16(pB + (KS) * 32 + 16, sb_ + 12288 + wave * 512);                            \
    WAITV(8);                                                                        \
    RAW_BAR();                                                                       \
    LGKM0();                                                                         \
    __builtin_amdgcn_s_setprio(1);                                                   \
    _Pragma("unroll")                                                                \
    for (int m = 0; m < 4; ++m)                                                      \
      _Pragma("unroll")                                                              \
      for (int n = 0; n < 4; ++n)                                                    \
        accf[m + 4][n] = MFMA_BF16(af[m], bf[n], accf[m + 4][n]);                    \
    __builtin_amdgcn_s_setprio(0);                                                   \
    RAW_BAR(); } while (0)

  STG2(0, 0); CFENCE(); STG2(1, 1); CFENCE(); STG2(2, 2);
  WAITV(8); RAW_BAR();

  for (int kt = 0; kt < 128; kt += 4) {
    int ks;
    ks = kt + 3 > 127 ? 127 : kt + 3;  PHA2(0, 3, ks); PHB2(0, 3, ks);
    ks = kt + 4 > 127 ? 127 : kt + 4;  PHA2(1, 0, ks); PHB2(1, 0, ks);
    ks = kt + 5 > 127 ? 127 : kt + 5;  PHA2(2, 1, ks); PHB2(2, 1, ks);
    ks = kt + 6 > 127 ? 127 : kt + 6;  PHA2(3, 2, ks); PHB2(3, 2, ks);
  }
  WAITV(0);
#undef STG2
#undef PHA2
#undef PHB2

#pragma unroll
  for (int m = 0; m < 8; ++m)
#pragma unroll
    for (int r4 = 0; r4 < 4; ++r4) {
      int mloc = wm * 128 + m * 16 + quad * 4 + r4;
      int tok = stok[mloc];
      float gt = sgt[mloc];
      float* basep = acc_out + ((size_t)b * S_ + tok) * D_ + n0 + wn * 64 + row16;
#pragma unroll
      for (int n = 0; n < 4; ++n) unsafeAtomicAdd(basep + n * 16, accf[m][n][r4] * gt);
    }
}

// ---------------- 5. fp32 accumulator -> output ----------------
__global__ __launch_bounds__(256) void conv_out_k(const float* __restrict__ acc,
                                                  void* __restrict__ out,
                                                  const int* __restrict__ flag) {
  const int isf32 = *flag;
  size_t i = ((size_t)blockIdx.x * 256 + threadIdx.x) * 4;
  float4 v = *(const float4*)(acc + i);
  if (isf32) {
    *(float4*)((float*)out + i) = v;
  } else {
    ushort4 o;
    o.x = f2bf(v.x); o.y = f2bf(v.y); o.z = f2bf(v.z); o.w = f2bf(v.w);
    *(ushort4*)((unsigned short*)out + i) = o;
  }
}

extern "C" void kernel_launch(void* const* d_in, const int* in_sizes, int n_in,
                              void* d_out, int out_size, void* d_ws, size_t ws_size,
                              hipStream_t stream) {
  const void* x_raw = d_in[0];
  const void* gate_w_raw = d_in[1];
  const void* w_gate_raw = d_in[2];
  const void* w_up_raw = d_in[3];
  const void* w_down_raw = d_in[4];

  char* ws = (char*)d_ws;
  size_t off = 0;
  auto alloc = [&](size_t bytes) { char* p = ws + off; off += (bytes + 255) & ~(size_t)255; return p; };
  float* acc = (float*)alloc((size_t)B_ * S_ * D_ * 4);          // 64 MB
  double* aff = (double*)alloc((size_t)B_ * E_ * S_ * 8);        // 1 MB
  int* sel_idx = (int*)alloc((size_t)NGROUPS * KCAP * 4);        // 128 KB
  float* sel_gate = (float*)alloc((size_t)NGROUPS * KCAP * 4);   // 128 KB
  int* flag = (int*)alloc(256);
  unsigned short* xb = (unsigned short*)alloc((size_t)B_ * S_ * D_ * 2);    // 33.5 MB
  unsigned short* wgb = (unsigned short*)alloc((size_t)E_ * I_ * D_ * 2);   // 67 MB
  unsigned short* wub = (unsigned short*)alloc((size_t)E_ * I_ * D_ * 2);   // 67 MB
  unsigned short* wdb = (unsigned short*)alloc((size_t)E_ * D_ * I_ * 2);   // 67 MB
  const size_t fixedBytes = off;
  const size_t hPerGroup = (size_t)KCAP * I_ * 2;  // 8 MB bf16
  int gch = 32;
  while (gch > 1 && fixedBytes + (size_t)gch * hPerGroup > ws_size) gch >>= 1;
  unsigned short* hbuf = (unsigned short*)(ws + fixedBytes);

  hipMemsetAsync(acc, 0, (size_t)B_ * S_ * D_ * 4, stream);
  hipMemsetAsync(sel_idx, 0, (size_t)NGROUPS * KCAP * 8, stream);

  probe_dtype_k<<<dim3(1), dim3(256), 0, stream>>>((const unsigned short*)x_raw, flag);
  conv_in_k<<<dim3((int)((size_t)B_ * S_ * D_ / 2048)), dim3(256), 0, stream>>>(x_raw, xb, flag);
  conv_in_k<<<dim3((int)((size_t)E_ * I_ * D_ / 2048)), dim3(256), 0, stream>>>(w_gate_raw, wgb, flag);
  conv_in_k<<<dim3((int)((size_t)E_ * I_ * D_ / 2048)), dim3(256), 0, stream>>>(w_up_raw, wub, flag);
  conv_in_k<<<dim3((int)((size_t)E_ * D_ * I_ / 2048)), dim3(256), 0, stream>>>(w_down_raw, wdb, flag);

  gate_softmax_k<<<dim3(B_ * S_ / 4), dim3(256), 0, stream>>>(x_raw, gate_w_raw, flag, aff);
  topk_sel_k<<<dim3(NGROUPS), dim3(256), 0, stream>>>(aff, sel_idx, sel_gate);
  for (int c0 = 0; c0 < NGROUPS; c0 += gch) {
    int gcur = (NGROUPS - c0) < gch ? (NGROUPS - c0) : gch;
    moe_gemm1<<<dim3(128, 1, gcur), dim3(512), 0, stream>>>(
        xb, wgb, wub, sel_idx, hbuf, c0);
    moe_gemm2<<<dim3(16, 1, gcur), dim3(512), 0, stream>>>(
        hbuf, wdb, sel_idx, sel_gate, acc, c0);
  }
  conv_out_k<<<dim3((int)((size_t)B_ * S_ * D_ / 4 / 256)), dim3(256), 0, stream>>>(acc, d_out, flag);
}